// Round 2
// baseline (183.755 us; speedup 1.0000x reference)
//
#include <hip/hip_runtime.h>
#include <math.h>

// RRoIAlign: features (8,32,160,160) f32, rois (1024,6) f32
// out (1024,32,8,64) f32.  POOLED_H=8, POOLED_W=64, SPATIAL_SCALE=0.25
//
// R2: thread-per-BIN (n,ph,pw), channel loop inside. Geometry computed once
// per bin (was 32x redundant -> VALUBusy 60%). Validity folded into weights
// (clamped gather addresses are always in-bounds). Non-temporal stores for
// the write-once output.
//
// NUMERICS (frozen from R1, absmax 0.0): geometry path uses
// fp contract(off) + reference op order; trig in double rounded to f32.
// round(floor(x+0.5)) pixel selection is ulp-sensitive — do not re-order.

#define C_ 32
#define H_ 160
#define W_ 160
#define PH_ 8
#define PW_ 64
#define HW_ (H_ * W_)

__global__ __launch_bounds__(256) void roi_prep(const float* __restrict__ rois,
                                                float* __restrict__ g, int N) {
#pragma clang fp contract(off)
    int n = blockIdx.x * 256 + threadIdx.x;
    if (n >= N) return;
    const float* r = rois + n * 6;
    float bidx = r[0];
    float cx = r[1], cy = r[2], hh = r[3], ww = r[4], ang = r[5];
    float theta = ang * 0.017453292519943295f;
    double td = (double)theta;
    float a = (float)cos(td);
    float s = (float)sin(td);
    float Sx = (ww * 0.25f) / 64.0f;
    float Sy = (hh * 0.25f) / 8.0f;
    float Dx = cx * 0.25f;
    float Dy = cy * 0.25f;
    float M00 = a * Sx;
    float M01 = s * Sy;
    float M02 = ((M00 * -32.0f) + (M01 * -4.0f)) + Dx;
    float M10 = (-s) * Sx;
    float M11 = a * Sy;
    float M12 = ((M10 * -32.0f) + (M11 * -4.0f)) + Dy;
    float* o = g + n * 8;
    o[0] = bidx;
    o[1] = M00; o[2] = M01; o[3] = M02;
    o[4] = M10; o[5] = M11; o[6] = M12;
    o[7] = 0.0f;
}

__global__ __launch_bounds__(256) void rroi_bins(const float* __restrict__ feat,
                                                 const float* __restrict__ g,
                                                 float* __restrict__ out,
                                                 int nbins) {
    int tid = blockIdx.x * 256 + threadIdx.x;
    if (tid >= nbins) return;
    int pw = tid & 63;
    int ph = (tid >> 6) & 7;
    int n  = tid >> 9;

    float wlt, wrt, wlb, wrb;
    int o_lt, o_rt, o_lb, o_rb;
    {
#pragma clang fp contract(off)
        const float* gg = g + n * 8;
        int   b   = (int)gg[0];
        float M00 = gg[1], M01 = gg[2], M02 = gg[3];
        float M10 = gg[4], M11 = gg[5], M12 = gg[6];

        float pwf  = (float)pw, phf = (float)ph;
        float pwf1 = pwf + 1.0f, phf1 = phf + 1.0f;

        // corners, reference op order: (M00*px + M01*py) + M02
        float X0 = (M00 * pwf  + M01 * phf ) + M02;
        float X1 = (M00 * pwf  + M01 * phf1) + M02;
        float X2 = (M00 * pwf1 + M01 * phf ) + M02;
        float X3 = (M00 * pwf1 + M01 * phf1) + M02;
        float Y0 = (M10 * pwf  + M11 * phf ) + M12;
        float Y1 = (M10 * pwf  + M11 * phf1) + M12;
        float Y2 = (M10 * pwf1 + M11 * phf ) + M12;
        float Y3 = (M10 * pwf1 + M11 * phf1) + M12;

        float minX = fminf(fminf(X0, X1), fminf(X2, X3));
        float maxX = fmaxf(fmaxf(X0, X1), fmaxf(X2, X3));
        float minY = fminf(fminf(Y0, Y1), fminf(Y2, Y3));
        float maxY = fmaxf(fmaxf(Y0, Y1), fmaxf(Y2, Y3));

        float left   = fmaxf(floorf(minX + 0.5f), 0.0f);
        float right  = fminf(floorf(maxX + 0.5f), (float)(W_ - 1));
        float top    = fmaxf(floorf(minY + 0.5f), 0.0f);
        float bottom = fminf(floorf(maxY + 0.5f), (float)(H_ - 1));

        float bcx = (left + right) * 0.5f;
        float bcy = (top + bottom) * 0.5f;
        float bl = floorf(bcx), br = ceilf(bcx);
        float bt = floorf(bcy), bb = ceilf(bcy);
        float rx = bcx - bl;   // exactly 0 or 0.5
        float ry = bcy - bt;

        bool v_l = (bl > -1.0f) && (bl < (float)W_);
        bool v_r = (br > -1.0f) && (br < (float)W_);
        bool v_t = (bt > -1.0f) && (bt < (float)H_);
        bool v_b = (bb > -1.0f) && (bb < (float)H_);

        float omrx = 1.0f - rx, omry = 1.0f - ry;
        // fold validity into weights: gather addr is clamped (always safe),
        // invalid corner contributes 0 via zero weight.
        wlt = (v_t && v_l) ? (omrx * omry) : 0.0f;
        wrt = (v_t && v_r) ? (rx   * omry) : 0.0f;
        wlb = (v_b && v_l) ? (omrx * ry  ) : 0.0f;
        wrb = (v_b && v_r) ? (rx   * ry  ) : 0.0f;

        int xl = (int)fminf(fmaxf(bl, 0.0f), (float)(W_ - 1));
        int xr = (int)fminf(fmaxf(br, 0.0f), (float)(W_ - 1));
        int yt = (int)fminf(fmaxf(bt, 0.0f), (float)(H_ - 1));
        int yb = (int)fminf(fmaxf(bb, 0.0f), (float)(H_ - 1));

        int base = b * (C_ * HW_);
        o_lt = base + yt * W_ + xl;
        o_rt = base + yt * W_ + xr;
        o_lb = base + yb * W_ + xl;
        o_rb = base + yb * W_ + xr;
    }

    // out[n][c][ph][pw]
    int obase = n * (C_ * PH_ * PW_) + ph * PW_ + pw;

#pragma unroll 8
    for (int c = 0; c < C_; ++c) {
        float vlt = feat[o_lt + c * HW_];
        float vrt = feat[o_rt + c * HW_];
        float vlb = feat[o_lb + c * HW_];
        float vrb = feat[o_rb + c * HW_];
        float o = wlt * vlt + wrt * vrt + wlb * vlb + wrb * vrb;
        __builtin_nontemporal_store(o, &out[obase + c * (PH_ * PW_)]);
    }
}

extern "C" void kernel_launch(void* const* d_in, const int* in_sizes, int n_in,
                              void* d_out, int out_size, void* d_ws,
                              size_t ws_size, hipStream_t stream) {
    const float* feat = (const float*)d_in[0];
    const float* rois = (const float*)d_in[1];
    float* out = (float*)d_out;
    float* g = (float*)d_ws;  // 1024 rois * 8 floats = 32 KB scratch
    int N = in_sizes[1] / 6;
    int nbins = N * PH_ * PW_;

    hipLaunchKernelGGL(roi_prep, dim3((N + 255) / 256), dim3(256), 0, stream,
                       rois, g, N);
    hipLaunchKernelGGL(rroi_bins, dim3((nbins + 255) / 256), dim3(256), 0,
                       stream, feat, g, out, nbins);
}

// Round 3
// 142.580 us; speedup vs baseline: 1.2888x; 1.2888x over previous
//
#include <hip/hip_runtime.h>
#include <hip/hip_fp16.h>
#include <math.h>

// RRoIAlign: features (8,32,160,160) f32, rois (1024,6) f32
// out (1024,32,8,64) f32.  POOLED_H=8, POOLED_W=64, SPATIAL_SCALE=0.25
//
// R3: 3-kernel pipeline.
//   roi_prep  (N threads)      : per-roi affine transform (trig in double).
//   bin_geom  (N*512 threads)  : per-bin geometry -> packed 16B record in ws
//                                {o_lt, dx|dyW<<16, w_lt|w_rt f16, w_lb|w_rb f16}.
//                                weights in {0,.25,.5,1} are f16-EXACT.
//   rroi_gather (out/2 threads): 2 channels/thread; 1 coalesced dwordx4 record
//                                load + 8 scattered gathers + exact-order blend.
// Rationale (R2 post-mortem): scattered gathers need wave-level parallelism —
// R2's 8K waves went latency-bound (VALU 7.6%). R3 restores R1's TLP (131K
// waves) while removing R1's ~200-instr/thread geometry recompute.
//
// NUMERICS (frozen, absmax 0.0): geometry uses fp contract(off) + reference op
// order; blend keeps reference add order with contract off. Do not re-order.

#define C_ 32
#define H_ 160
#define W_ 160
#define PH_ 8
#define PW_ 64
#define HW_ (H_ * W_)
#define NB_ (PH_ * PW_)  // 512 bins per roi

__global__ __launch_bounds__(256) void roi_prep(const float* __restrict__ rois,
                                                float* __restrict__ g, int N) {
#pragma clang fp contract(off)
    int n = blockIdx.x * 256 + threadIdx.x;
    if (n >= N) return;
    const float* r = rois + n * 6;
    float bidx = r[0];
    float cx = r[1], cy = r[2], hh = r[3], ww = r[4], ang = r[5];
    float theta = ang * 0.017453292519943295f;
    double td = (double)theta;
    float a = (float)cos(td);
    float s = (float)sin(td);
    float Sx = (ww * 0.25f) / 64.0f;
    float Sy = (hh * 0.25f) / 8.0f;
    float Dx = cx * 0.25f;
    float Dy = cy * 0.25f;
    float M00 = a * Sx;
    float M01 = s * Sy;
    float M02 = ((M00 * -32.0f) + (M01 * -4.0f)) + Dx;
    float M10 = (-s) * Sx;
    float M11 = a * Sy;
    float M12 = ((M10 * -32.0f) + (M11 * -4.0f)) + Dy;
    float* o = g + n * 8;
    o[0] = bidx;
    o[1] = M00; o[2] = M01; o[3] = M02;
    o[4] = M10; o[5] = M11; o[6] = M12;
    o[7] = 0.0f;
}

// One thread per bin (n,ph,pw): full geometry -> packed 16B record.
__global__ __launch_bounds__(256) void bin_geom(const float* __restrict__ g,
                                                int4* __restrict__ rec,
                                                int nbins) {
#pragma clang fp contract(off)
    int tid = blockIdx.x * 256 + threadIdx.x;
    if (tid >= nbins) return;
    int pw = tid & 63;
    int ph = (tid >> 6) & 7;
    int n  = tid >> 9;

    const float* gg = g + n * 8;
    int   b   = (int)gg[0];
    float M00 = gg[1], M01 = gg[2], M02 = gg[3];
    float M10 = gg[4], M11 = gg[5], M12 = gg[6];

    float pwf  = (float)pw, phf = (float)ph;
    float pwf1 = pwf + 1.0f, phf1 = phf + 1.0f;

    // corners, reference op order: (M00*px + M01*py) + M02
    float X0 = (M00 * pwf  + M01 * phf ) + M02;
    float X1 = (M00 * pwf  + M01 * phf1) + M02;
    float X2 = (M00 * pwf1 + M01 * phf ) + M02;
    float X3 = (M00 * pwf1 + M01 * phf1) + M02;
    float Y0 = (M10 * pwf  + M11 * phf ) + M12;
    float Y1 = (M10 * pwf  + M11 * phf1) + M12;
    float Y2 = (M10 * pwf1 + M11 * phf ) + M12;
    float Y3 = (M10 * pwf1 + M11 * phf1) + M12;

    float minX = fminf(fminf(X0, X1), fminf(X2, X3));
    float maxX = fmaxf(fmaxf(X0, X1), fmaxf(X2, X3));
    float minY = fminf(fminf(Y0, Y1), fminf(Y2, Y3));
    float maxY = fmaxf(fmaxf(Y0, Y1), fmaxf(Y2, Y3));

    float left   = fmaxf(floorf(minX + 0.5f), 0.0f);
    float right  = fminf(floorf(maxX + 0.5f), (float)(W_ - 1));
    float top    = fmaxf(floorf(minY + 0.5f), 0.0f);
    float bottom = fminf(floorf(maxY + 0.5f), (float)(H_ - 1));

    float bcx = (left + right) * 0.5f;
    float bcy = (top + bottom) * 0.5f;
    float bl = floorf(bcx), br = ceilf(bcx);
    float bt = floorf(bcy), bb = ceilf(bcy);
    float rx = bcx - bl;  // exactly 0 or 0.5
    float ry = bcy - bt;

    bool v_l = (bl > -1.0f) && (bl < (float)W_);
    bool v_r = (br > -1.0f) && (br < (float)W_);
    bool v_t = (bt > -1.0f) && (bt < (float)H_);
    bool v_b = (bb > -1.0f) && (bb < (float)H_);

    float omrx = 1.0f - rx, omry = 1.0f - ry;
    float wlt = (v_t && v_l) ? (omrx * omry) : 0.0f;
    float wrt = (v_t && v_r) ? (rx   * omry) : 0.0f;
    float wlb = (v_b && v_l) ? (omrx * ry  ) : 0.0f;
    float wrb = (v_b && v_r) ? (rx   * ry  ) : 0.0f;

    int xl = (int)fminf(fmaxf(bl, 0.0f), (float)(W_ - 1));
    int xr = (int)fminf(fmaxf(br, 0.0f), (float)(W_ - 1));
    int yt = (int)fminf(fmaxf(bt, 0.0f), (float)(H_ - 1));
    int yb = (int)fminf(fmaxf(bb, 0.0f), (float)(H_ - 1));

    int o_lt = b * (C_ * HW_) + yt * W_ + xl;
    int dx   = xr - xl;          // 0 or 1
    int dyw  = (yb - yt) * W_;   // 0 or 160
    // weights {0,.25,.5,1} -> f16 exact
    uint w01 = (uint)__half_as_ushort(__float2half(wlt)) |
               ((uint)__half_as_ushort(__float2half(wrt)) << 16);
    uint w23 = (uint)__half_as_ushort(__float2half(wlb)) |
               ((uint)__half_as_ushort(__float2half(wrb)) << 16);

    int4 rc;
    rc.x = o_lt;
    rc.y = dx | (dyw << 16);
    rc.z = (int)w01;
    rc.w = (int)w23;
    rec[tid] = rc;
}

// One thread per 2 output elements (channels cl and cl+16 of one bin).
__global__ __launch_bounds__(256) void rroi_gather(
    const float* __restrict__ feat, const int4* __restrict__ rec,
    float* __restrict__ out, int nthreads) {
#pragma clang fp contract(off)
    int t = blockIdx.x * 256 + threadIdx.x;
    if (t >= nthreads) return;
    int pw = t & 63;
    int ph = (t >> 6) & 7;
    int cl = (t >> 9) & 15;  // channels cl and cl+16
    int n  = t >> 13;

    int bin = (n << 9) | (ph << 6) | pw;  // consecutive lanes -> coalesced
    int4 rc = rec[bin];

    int o_lt = rc.x;
    int dx   = rc.y & 0xffff;
    int dyw  = (int)((uint)rc.y >> 16);

    union { uint u; __half2 h; } u01, u23;
    u01.u = (uint)rc.z;
    u23.u = (uint)rc.w;
    float wlt = __low2float(u01.h), wrt = __high2float(u01.h);
    float wlb = __low2float(u23.h), wrb = __high2float(u23.h);

    const float* f0 = feat + o_lt + cl * HW_;
    const float* f1 = f0 + 16 * HW_;

    // 8 independent gathers -> MLP
    float a0 = f0[0];
    float a1 = f0[dx];
    float a2 = f0[dyw];
    float a3 = f0[dx + dyw];
    float b0 = f1[0];
    float b1 = f1[dx];
    float b2 = f1[dyw];
    float b3 = f1[dx + dyw];

    // reference add order, contract off -> bit-exact vs numpy
    float o0 = ((wlt * a0 + wrt * a1) + wlb * a2) + wrb * a3;
    float o1 = ((wlt * b0 + wrt * b1) + wlb * b2) + wrb * b3;

    int obase = n * (C_ * NB_) + cl * NB_ + (ph << 6) + pw;
    __builtin_nontemporal_store(o0, &out[obase]);
    __builtin_nontemporal_store(o1, &out[obase + 16 * NB_]);
}

// Fallback (R1, known-good 80us): thread per output, full geometry recompute.
__global__ __launch_bounds__(256) void rroi_fallback(
    const float* __restrict__ feat, const float* __restrict__ g,
    float* __restrict__ out, int total) {
#pragma clang fp contract(off)
    int idx = blockIdx.x * 256 + threadIdx.x;
    if (idx >= total) return;
    int pw = idx & 63;
    int ph = (idx >> 6) & 7;
    int c  = (idx >> 9) & 31;
    int n  = idx >> 14;

    const float* gg = g + n * 8;
    int   b   = (int)gg[0];
    float M00 = gg[1], M01 = gg[2], M02 = gg[3];
    float M10 = gg[4], M11 = gg[5], M12 = gg[6];

    float pwf  = (float)pw, phf = (float)ph;
    float pwf1 = pwf + 1.0f, phf1 = phf + 1.0f;
    float X0 = (M00 * pwf  + M01 * phf ) + M02;
    float X1 = (M00 * pwf  + M01 * phf1) + M02;
    float X2 = (M00 * pwf1 + M01 * phf ) + M02;
    float X3 = (M00 * pwf1 + M01 * phf1) + M02;
    float Y0 = (M10 * pwf  + M11 * phf ) + M12;
    float Y1 = (M10 * pwf  + M11 * phf1) + M12;
    float Y2 = (M10 * pwf1 + M11 * phf ) + M12;
    float Y3 = (M10 * pwf1 + M11 * phf1) + M12;
    float minX = fminf(fminf(X0, X1), fminf(X2, X3));
    float maxX = fmaxf(fmaxf(X0, X1), fmaxf(X2, X3));
    float minY = fminf(fminf(Y0, Y1), fminf(Y2, Y3));
    float maxY = fmaxf(fmaxf(Y0, Y1), fmaxf(Y2, Y3));
    float left   = fmaxf(floorf(minX + 0.5f), 0.0f);
    float right  = fminf(floorf(maxX + 0.5f), (float)(W_ - 1));
    float top    = fmaxf(floorf(minY + 0.5f), 0.0f);
    float bottom = fminf(floorf(maxY + 0.5f), (float)(H_ - 1));
    float bcx = (left + right) * 0.5f;
    float bcy = (top + bottom) * 0.5f;
    float bl = floorf(bcx), br = ceilf(bcx);
    float bt = floorf(bcy), bb = ceilf(bcy);
    float rx = bcx - bl;
    float ry = bcy - bt;
    const float* fc = feat + (size_t)(b * C_ + c) * HW_;
    auto gat = [&](float yi, float xi) -> float {
        bool valid = (yi > -1.0f) && (xi > -1.0f) && (yi < (float)H_) &&
                     (xi < (float)W_);
        int yc = (int)fminf(fmaxf(yi, 0.0f), (float)(H_ - 1));
        int xc = (int)fminf(fmaxf(xi, 0.0f), (float)(W_ - 1));
        float v = fc[yc * W_ + xc];
        return valid ? v : 0.0f;
    };
    float vlt = gat(bt, bl);
    float vrt = gat(bt, br);
    float vlb = gat(bb, bl);
    float vrb = gat(bb, br);
    float omrx = 1.0f - rx, omry = 1.0f - ry;
    float o = (((omrx * omry) * vlt + (rx * omry) * vrt) + (omrx * ry) * vlb) +
              (rx * ry) * vrb;
    out[idx] = o;
}

extern "C" void kernel_launch(void* const* d_in, const int* in_sizes, int n_in,
                              void* d_out, int out_size, void* d_ws,
                              size_t ws_size, hipStream_t stream) {
    const float* feat = (const float*)d_in[0];
    const float* rois = (const float*)d_in[1];
    float* out = (float*)d_out;
    int N = in_sizes[1] / 6;
    int nbins = N * NB_;
    size_t recBytes = (size_t)nbins * sizeof(int4);
    size_t needed = recBytes + (size_t)N * 8 * sizeof(float);

    if (ws_size >= needed) {
        int4* rec = (int4*)d_ws;
        float* g = (float*)((char*)d_ws + recBytes);
        hipLaunchKernelGGL(roi_prep, dim3((N + 255) / 256), dim3(256), 0,
                           stream, rois, g, N);
        hipLaunchKernelGGL(bin_geom, dim3((nbins + 255) / 256), dim3(256), 0,
                           stream, g, rec, nbins);
        int nthreads = out_size / 2;
        hipLaunchKernelGGL(rroi_gather, dim3((nthreads + 255) / 256), dim3(256),
                           0, stream, feat, rec, out, nthreads);
    } else {
        float* g = (float*)d_ws;  // N*8 floats
        hipLaunchKernelGGL(roi_prep, dim3((N + 255) / 256), dim3(256), 0,
                           stream, rois, g, N);
        hipLaunchKernelGGL(rroi_fallback, dim3((out_size + 255) / 256),
                           dim3(256), 0, stream, feat, g, out, out_size);
    }
}

// Round 4
// 107.705 us; speedup vs baseline: 1.7061x; 1.3238x over previous
//
#include <hip/hip_runtime.h>
#include <math.h>

// RRoIAlign: features (8,32,160,160) f32, rois (1024,6) f32
// out (1024,32,8,64) f32.  POOLED_H=8, POOLED_W=64, SPATIAL_SCALE=0.25
//
// R4: NHWC-transpose pipeline (R3 post-mortem: gathers were L1-line-serialized,
// ~40 lines/wave-gather with lane=pw in NCHW; all pipes <30% busy).
//   roi_prep   : per-roi affine transform (trig in double).       [~3 us]
//   transpose  : NCHW -> NHWC (B,HW,32), LDS 32x65 tile.          [~10 us]
//   rroi_nhwc  : block = 64 bins of one roi. Geometry computed once per bin
//                by t<64 into LDS; gather lanes = (2 bins x 32 ch) so every
//                corner gather is 2x128B-aligned lines per wave; blend; LDS
//                out-tile transpose -> coalesced 256B stores.     [~15 us]
//
// NUMERICS (frozen since R1, absmax 0.0): geometry fp contract(off) +
// reference op order; trig double->f32; blend order ((w0*a0+w1*a1)+w2*a2)+w3*a3
// with contract off. Do not re-order.

#define C_ 32
#define H_ 160
#define W_ 160
#define PH_ 8
#define PW_ 64
#define HW_ (H_ * W_)
#define NB_ (PH_ * PW_)  // 512 bins per roi

__global__ __launch_bounds__(256) void roi_prep(const float* __restrict__ rois,
                                                float* __restrict__ g, int N) {
#pragma clang fp contract(off)
    int n = blockIdx.x * 256 + threadIdx.x;
    if (n >= N) return;
    const float* r = rois + n * 6;
    float bidx = r[0];
    float cx = r[1], cy = r[2], hh = r[3], ww = r[4], ang = r[5];
    float theta = ang * 0.017453292519943295f;
    double td = (double)theta;
    float a = (float)cos(td);
    float s = (float)sin(td);
    float Sx = (ww * 0.25f) / 64.0f;
    float Sy = (hh * 0.25f) / 8.0f;
    float Dx = cx * 0.25f;
    float Dy = cy * 0.25f;
    float M00 = a * Sx;
    float M01 = s * Sy;
    float M02 = ((M00 * -32.0f) + (M01 * -4.0f)) + Dx;
    float M10 = (-s) * Sx;
    float M11 = a * Sy;
    float M12 = ((M10 * -32.0f) + (M11 * -4.0f)) + Dy;
    float* o = g + n * 8;
    o[0] = bidx;
    o[1] = M00; o[2] = M01; o[3] = M02;
    o[4] = M10; o[5] = M11; o[6] = M12;
    o[7] = 0.0f;
}

// NCHW (B,32,25600) -> NHWC (B,25600,32). Tile: 32 c x 64 hw via LDS.
__global__ __launch_bounds__(256) void transpose_nhwc(
    const float* __restrict__ feat, float* __restrict__ ft, int B) {
    __shared__ float tile[C_][65];  // +1 pad: write-phase reads stride-65
    int b   = blockIdx.y;
    int hw0 = blockIdx.x * 64;
    int t   = threadIdx.x;
    int w   = t & 63;
    int c0  = t >> 6;  // 0..3
#pragma unroll
    for (int i = 0; i < 8; ++i) {
        int c = c0 + i * 4;
        tile[c][w] = feat[((b * C_ + c) * HW_) + hw0 + w];
    }
    __syncthreads();
    int c  = t & 31;
    int p0 = t >> 5;  // 0..7
#pragma unroll
    for (int i = 0; i < 8; ++i) {
        int p = p0 + i * 8;
        ft[((size_t)b * HW_ + hw0 + p) * C_ + c] = tile[c][p];
    }
}

// Block = 64 consecutive bins of one roi. 256 threads.
__global__ __launch_bounds__(256) void rroi_nhwc(
    const float* __restrict__ ft, const float* __restrict__ g,
    float* __restrict__ out) {
    __shared__ int   s_pos[64];
    __shared__ int   s_dxy[64];
    __shared__ float4 s_w[64];
    __shared__ float s_out[64 * 33];  // [bin][c], pad 33

    int blk = blockIdx.x;
    int n   = blk >> 3;
    int seg = blk & 7;          // which 64-bin segment of the roi
    int t   = threadIdx.x;

    if (t < 64) {
#pragma clang fp contract(off)
        int bin = seg * 64 + t;     // bin index within roi = ph*64+pw
        int pw = bin & 63;
        int ph = bin >> 6;
        const float* gg = g + n * 8;
        int   b   = (int)gg[0];
        float M00 = gg[1], M01 = gg[2], M02 = gg[3];
        float M10 = gg[4], M11 = gg[5], M12 = gg[6];

        float pwf  = (float)pw, phf = (float)ph;
        float pwf1 = pwf + 1.0f, phf1 = phf + 1.0f;
        // corners, reference op order: (M00*px + M01*py) + M02
        float X0 = (M00 * pwf  + M01 * phf ) + M02;
        float X1 = (M00 * pwf  + M01 * phf1) + M02;
        float X2 = (M00 * pwf1 + M01 * phf ) + M02;
        float X3 = (M00 * pwf1 + M01 * phf1) + M02;
        float Y0 = (M10 * pwf  + M11 * phf ) + M12;
        float Y1 = (M10 * pwf  + M11 * phf1) + M12;
        float Y2 = (M10 * pwf1 + M11 * phf ) + M12;
        float Y3 = (M10 * pwf1 + M11 * phf1) + M12;

        float minX = fminf(fminf(X0, X1), fminf(X2, X3));
        float maxX = fmaxf(fmaxf(X0, X1), fmaxf(X2, X3));
        float minY = fminf(fminf(Y0, Y1), fminf(Y2, Y3));
        float maxY = fmaxf(fmaxf(Y0, Y1), fmaxf(Y2, Y3));

        float left   = fmaxf(floorf(minX + 0.5f), 0.0f);
        float right  = fminf(floorf(maxX + 0.5f), (float)(W_ - 1));
        float top    = fmaxf(floorf(minY + 0.5f), 0.0f);
        float bottom = fminf(floorf(maxY + 0.5f), (float)(H_ - 1));

        float bcx = (left + right) * 0.5f;
        float bcy = (top + bottom) * 0.5f;
        float bl = floorf(bcx), br = ceilf(bcx);
        float bt = floorf(bcy), bb = ceilf(bcy);
        float rx = bcx - bl;  // exactly 0 or 0.5
        float ry = bcy - bt;

        bool v_l = (bl > -1.0f) && (bl < (float)W_);
        bool v_r = (br > -1.0f) && (br < (float)W_);
        bool v_t = (bt > -1.0f) && (bt < (float)H_);
        bool v_b = (bb > -1.0f) && (bb < (float)H_);

        float omrx = 1.0f - rx, omry = 1.0f - ry;
        float4 w4;
        w4.x = (v_t && v_l) ? (omrx * omry) : 0.0f;
        w4.y = (v_t && v_r) ? (rx   * omry) : 0.0f;
        w4.z = (v_b && v_l) ? (omrx * ry  ) : 0.0f;
        w4.w = (v_b && v_r) ? (rx   * ry  ) : 0.0f;

        int xl = (int)fminf(fmaxf(bl, 0.0f), (float)(W_ - 1));
        int xr = (int)fminf(fmaxf(br, 0.0f), (float)(W_ - 1));
        int yt = (int)fminf(fmaxf(bt, 0.0f), (float)(H_ - 1));
        int yb = (int)fminf(fmaxf(bb, 0.0f), (float)(H_ - 1));

        s_pos[t] = b * HW_ + yt * W_ + xl;          // NHWC pixel index
        s_dxy[t] = (xr - xl) | (((yb - yt) * W_) << 16);
        s_w[t]   = w4;
    }
    __syncthreads();

    // Gather+blend: wave = 2 bins x 32 channels; each corner gather per wave
    // touches exactly 2 aligned 128B lines.
    int c = t & 31;
    int bin_base = (t >> 5) & 1;   // which bin of the pair in this half-wave
    int wave = t >> 6;             // 0..3
#pragma unroll
    for (int j = 0; j < 8; ++j) {
#pragma clang fp contract(off)
        int bl_ = j * 8 + wave * 2 + bin_base;  // bin_local 0..63
        int pos = s_pos[bl_];
        int d   = s_dxy[bl_];
        int dx  = d & 0xffff;
        int dyw = (int)((unsigned)d >> 16);
        float4 w4 = s_w[bl_];

        const float* f0 = ft + (size_t)pos * C_ + c;
        float a0 = f0[0];
        float a1 = f0[dx * C_];
        float a2 = f0[dyw * C_];
        float a3 = f0[(dx + dyw) * C_];

        float o = ((w4.x * a0 + w4.y * a1) + w4.z * a2) + w4.w * a3;
        s_out[bl_ * 33 + c] = o;
    }
    __syncthreads();

    // Coalesced store: out[n][c][seg*64 + bin_local]
    int obase = n * (C_ * NB_) + seg * 64;
#pragma unroll
    for (int i = 0; i < 8; ++i) {
        int idx = i * 256 + t;
        int cc = idx >> 6;
        int bb = idx & 63;
        __builtin_nontemporal_store(s_out[bb * 33 + cc],
                                    &out[obase + cc * NB_ + bb]);
    }
}

// Fallback (R1, known-good): thread per output, full geometry recompute.
__global__ __launch_bounds__(256) void rroi_fallback(
    const float* __restrict__ feat, const float* __restrict__ g,
    float* __restrict__ out, int total) {
#pragma clang fp contract(off)
    int idx = blockIdx.x * 256 + threadIdx.x;
    if (idx >= total) return;
    int pw = idx & 63;
    int ph = (idx >> 6) & 7;
    int c  = (idx >> 9) & 31;
    int n  = idx >> 14;
    const float* gg = g + n * 8;
    int   b   = (int)gg[0];
    float M00 = gg[1], M01 = gg[2], M02 = gg[3];
    float M10 = gg[4], M11 = gg[5], M12 = gg[6];
    float pwf  = (float)pw, phf = (float)ph;
    float pwf1 = pwf + 1.0f, phf1 = phf + 1.0f;
    float X0 = (M00 * pwf  + M01 * phf ) + M02;
    float X1 = (M00 * pwf  + M01 * phf1) + M02;
    float X2 = (M00 * pwf1 + M01 * phf ) + M02;
    float X3 = (M00 * pwf1 + M01 * phf1) + M02;
    float Y0 = (M10 * pwf  + M11 * phf ) + M12;
    float Y1 = (M10 * pwf  + M11 * phf1) + M12;
    float Y2 = (M10 * pwf1 + M11 * phf ) + M12;
    float Y3 = (M10 * pwf1 + M11 * phf1) + M12;
    float minX = fminf(fminf(X0, X1), fminf(X2, X3));
    float maxX = fmaxf(fmaxf(X0, X1), fmaxf(X2, X3));
    float minY = fminf(fminf(Y0, Y1), fminf(Y2, Y3));
    float maxY = fmaxf(fmaxf(Y0, Y1), fmaxf(Y2, Y3));
    float left   = fmaxf(floorf(minX + 0.5f), 0.0f);
    float right  = fminf(floorf(maxX + 0.5f), (float)(W_ - 1));
    float top    = fmaxf(floorf(minY + 0.5f), 0.0f);
    float bottom = fminf(floorf(maxY + 0.5f), (float)(H_ - 1));
    float bcx = (left + right) * 0.5f;
    float bcy = (top + bottom) * 0.5f;
    float bl = floorf(bcx), br = ceilf(bcx);
    float bt = floorf(bcy), bb = ceilf(bcy);
    float rx = bcx - bl;
    float ry = bcy - bt;
    const float* fc = feat + (size_t)(b * C_ + c) * HW_;
    auto gat = [&](float yi, float xi) -> float {
        bool valid = (yi > -1.0f) && (xi > -1.0f) && (yi < (float)H_) &&
                     (xi < (float)W_);
        int yc = (int)fminf(fmaxf(yi, 0.0f), (float)(H_ - 1));
        int xc = (int)fminf(fmaxf(xi, 0.0f), (float)(W_ - 1));
        float v = fc[yc * W_ + xc];
        return valid ? v : 0.0f;
    };
    float vlt = gat(bt, bl);
    float vrt = gat(bt, br);
    float vlb = gat(bb, bl);
    float vrb = gat(bb, br);
    float omrx = 1.0f - rx, omry = 1.0f - ry;
    float o = (((omrx * omry) * vlt + (rx * omry) * vrt) + (omrx * ry) * vlb) +
              (rx * ry) * vrb;
    out[idx] = o;
}

extern "C" void kernel_launch(void* const* d_in, const int* in_sizes, int n_in,
                              void* d_out, int out_size, void* d_ws,
                              size_t ws_size, hipStream_t stream) {
    const float* feat = (const float*)d_in[0];
    const float* rois = (const float*)d_in[1];
    float* out = (float*)d_out;
    int N = in_sizes[1] / 6;
    int B = in_sizes[0] / (C_ * HW_);

    size_t gBytes  = (size_t)N * 8 * sizeof(float);
    size_t ftBytes = (size_t)B * HW_ * C_ * sizeof(float);
    size_t needed  = gBytes + ftBytes;

    if (ws_size >= needed) {
        float* g  = (float*)d_ws;
        float* ft = (float*)((char*)d_ws + gBytes);
        hipLaunchKernelGGL(roi_prep, dim3((N + 255) / 256), dim3(256), 0,
                           stream, rois, g, N);
        hipLaunchKernelGGL(transpose_nhwc, dim3(HW_ / 64, B), dim3(256), 0,
                           stream, feat, ft, B);
        hipLaunchKernelGGL(rroi_nhwc, dim3(N * 8), dim3(256), 0, stream, ft, g,
                           out);
    } else {
        float* g = (float*)d_ws;  // N*8 floats
        hipLaunchKernelGGL(roi_prep, dim3((N + 255) / 256), dim3(256), 0,
                           stream, rois, g, N);
        hipLaunchKernelGGL(rroi_fallback, dim3((out_size + 255) / 256),
                           dim3(256), 0, stream, feat, g, out, out_size);
    }
}

// Round 6
// 105.777 us; speedup vs baseline: 1.7372x; 1.0182x over previous
//
#include <hip/hip_runtime.h>
#include <math.h>

// RRoIAlign: features (8,32,160,160) f32, rois (1024,6) f32
// out (1024,32,8,64) f32.  POOLED_H=8, POOLED_W=64, SPATIAL_SCALE=0.25
//
// R5b pipeline (2 kernels) — R5 with the nontemporal-store type fixed
// (__builtin_nontemporal_store needs a NATIVE vector type, not HIP float4).
//   transpose_nhwc : NCHW -> NHWC (B,HW,32) with dwordx4 in/out; first 4
//                    blocks ALSO compute per-roi affine transforms g[].
//   rroi_nhwc      : block = 64 bins of one roi. t<64 computes bin geometry
//                    into LDS; gather = 8 bins x 8 lanes, float4/lane ->
//                    dwordx4 gathers; blend; LDS [c][bin] tile -> dwordx4
//                    nontemporal coalesced stores.
//
// NUMERICS (frozen since R1, absmax 0.0): geometry fp contract(off) +
// reference op order; trig double->f32; blend ((w0*a+w1*b)+w2*c)+w3*d with
// contract off, applied per channel component. Do not re-order.

#define C_ 32
#define H_ 160
#define W_ 160
#define PH_ 8
#define PW_ 64
#define HW_ (H_ * W_)
#define NB_ (PH_ * PW_)  // 512 bins per roi

typedef float nfloat4 __attribute__((ext_vector_type(4)));  // native vec4

__device__ __forceinline__ void roi_transform(const float* __restrict__ rois,
                                              int n, float* __restrict__ g) {
#pragma clang fp contract(off)
    const float* r = rois + n * 6;
    float bidx = r[0];
    float cx = r[1], cy = r[2], hh = r[3], ww = r[4], ang = r[5];
    float theta = ang * 0.017453292519943295f;
    double td = (double)theta;
    float a = (float)cos(td);
    float s = (float)sin(td);
    float Sx = (ww * 0.25f) / 64.0f;
    float Sy = (hh * 0.25f) / 8.0f;
    float Dx = cx * 0.25f;
    float Dy = cy * 0.25f;
    float M00 = a * Sx;
    float M01 = s * Sy;
    float M02 = ((M00 * -32.0f) + (M01 * -4.0f)) + Dx;
    float M10 = (-s) * Sx;
    float M11 = a * Sy;
    float M12 = ((M10 * -32.0f) + (M11 * -4.0f)) + Dy;
    float* o = g + n * 8;
    o[0] = bidx;
    o[1] = M00; o[2] = M01; o[3] = M02;
    o[4] = M10; o[5] = M11; o[6] = M12;
    o[7] = 0.0f;
}

// NCHW (B,32,25600) -> NHWC (B,25600,32), dwordx4 both sides.
// Blocks (x<ceil(N/256), y==0) also compute roi transforms into g.
__global__ __launch_bounds__(256) void transpose_nhwc(
    const float* __restrict__ feat, float* __restrict__ ft,
    const float* __restrict__ rois, float* __restrict__ g, int N) {
    __shared__ float tile[C_][65];
    int t = threadIdx.x;

    // folded roi prep (independent of transpose work below)
    if (blockIdx.y == 0) {
        int n = blockIdx.x * 256 + t;
        if (n < N) roi_transform(rois, n, g);
    }

    int b   = blockIdx.y;
    int hw0 = blockIdx.x * 64;

    // read: 512 float4-units along hw. unit v: c=v>>4, w4=(v&15)*4
#pragma unroll
    for (int i = 0; i < 2; ++i) {
        int v  = i * 256 + t;
        int c  = v >> 4;
        int w4 = (v & 15) * 4;
        const nfloat4 f =
            *(const nfloat4*)&feat[((b * C_ + c) * HW_) + hw0 + w4];
        tile[c][w4 + 0] = f.x;
        tile[c][w4 + 1] = f.y;
        tile[c][w4 + 2] = f.z;
        tile[c][w4 + 3] = f.w;
    }
    __syncthreads();

    // write: 512 float4-units along c. unit u: p=u>>3, c4=u&7
#pragma unroll
    for (int i = 0; i < 2; ++i) {
        int u  = i * 256 + t;
        int p  = u >> 3;
        int c4 = (u & 7) * 4;
        nfloat4 o;
        o.x = tile[c4 + 0][p];
        o.y = tile[c4 + 1][p];
        o.z = tile[c4 + 2][p];
        o.w = tile[c4 + 3][p];
        *(nfloat4*)&ft[((size_t)b * HW_ + hw0 + p) * C_ + c4] = o;
    }
}

// Block = 64 consecutive bins of one roi. 256 threads.
__global__ __launch_bounds__(256) void rroi_nhwc(
    const float* __restrict__ ft, const float* __restrict__ g,
    float* __restrict__ out) {
    __shared__ int     s_pos[64];
    __shared__ int     s_dxy[64];
    __shared__ float4  s_w[64];
    __shared__ float   s_out[C_ * 65];  // [c][bin], pad 65 (<=2-way, free)

    int blk = blockIdx.x;
    int n   = blk >> 3;
    int seg = blk & 7;
    int t   = threadIdx.x;

    if (t < 64) {
#pragma clang fp contract(off)
        int bin = seg * 64 + t;  // = ph*64+pw
        int pw = bin & 63;
        int ph = bin >> 6;
        const float* gg = g + n * 8;
        int   b   = (int)gg[0];
        float M00 = gg[1], M01 = gg[2], M02 = gg[3];
        float M10 = gg[4], M11 = gg[5], M12 = gg[6];

        float pwf  = (float)pw, phf = (float)ph;
        float pwf1 = pwf + 1.0f, phf1 = phf + 1.0f;
        // corners, reference op order: (M00*px + M01*py) + M02
        float X0 = (M00 * pwf  + M01 * phf ) + M02;
        float X1 = (M00 * pwf  + M01 * phf1) + M02;
        float X2 = (M00 * pwf1 + M01 * phf ) + M02;
        float X3 = (M00 * pwf1 + M01 * phf1) + M02;
        float Y0 = (M10 * pwf  + M11 * phf ) + M12;
        float Y1 = (M10 * pwf  + M11 * phf1) + M12;
        float Y2 = (M10 * pwf1 + M11 * phf ) + M12;
        float Y3 = (M10 * pwf1 + M11 * phf1) + M12;

        float minX = fminf(fminf(X0, X1), fminf(X2, X3));
        float maxX = fmaxf(fmaxf(X0, X1), fmaxf(X2, X3));
        float minY = fminf(fminf(Y0, Y1), fminf(Y2, Y3));
        float maxY = fmaxf(fmaxf(Y0, Y1), fmaxf(Y2, Y3));

        float left   = fmaxf(floorf(minX + 0.5f), 0.0f);
        float right  = fminf(floorf(maxX + 0.5f), (float)(W_ - 1));
        float top    = fmaxf(floorf(minY + 0.5f), 0.0f);
        float bottom = fminf(floorf(maxY + 0.5f), (float)(H_ - 1));

        float bcx = (left + right) * 0.5f;
        float bcy = (top + bottom) * 0.5f;
        float bl = floorf(bcx), br = ceilf(bcx);
        float bt = floorf(bcy), bb = ceilf(bcy);
        float rx = bcx - bl;  // exactly 0 or 0.5
        float ry = bcy - bt;

        bool v_l = (bl > -1.0f) && (bl < (float)W_);
        bool v_r = (br > -1.0f) && (br < (float)W_);
        bool v_t = (bt > -1.0f) && (bt < (float)H_);
        bool v_b = (bb > -1.0f) && (bb < (float)H_);

        float omrx = 1.0f - rx, omry = 1.0f - ry;
        float4 w4;
        w4.x = (v_t && v_l) ? (omrx * omry) : 0.0f;
        w4.y = (v_t && v_r) ? (rx   * omry) : 0.0f;
        w4.z = (v_b && v_l) ? (omrx * ry  ) : 0.0f;
        w4.w = (v_b && v_r) ? (rx   * ry  ) : 0.0f;

        int xl = (int)fminf(fmaxf(bl, 0.0f), (float)(W_ - 1));
        int xr = (int)fminf(fmaxf(br, 0.0f), (float)(W_ - 1));
        int yt = (int)fminf(fmaxf(bt, 0.0f), (float)(H_ - 1));
        int yb = (int)fminf(fmaxf(bb, 0.0f), (float)(H_ - 1));

        s_pos[t] = b * HW_ + yt * W_ + xl;  // NHWC pixel index
        s_dxy[t] = (xr - xl) | (((yb - yt) * W_) << 16);
        s_w[t]   = w4;
    }
    __syncthreads();

    // Gather+blend: 512 float4-units. unit u: bin=u>>3, c4=u&7.
    // Per corner per wave: 8 bins x 128B-aligned line; dwordx4 loads.
#pragma unroll
    for (int i = 0; i < 2; ++i) {
#pragma clang fp contract(off)
        int u   = i * 256 + t;
        int bl_ = u >> 3;
        int c4  = u & 7;
        int pos = s_pos[bl_];
        int d   = s_dxy[bl_];
        int dx  = d & 0xffff;
        int dyw = (int)((unsigned)d >> 16);
        float4 w4 = s_w[bl_];

        const nfloat4* f0 = (const nfloat4*)(ft + (size_t)pos * C_) + c4;
        nfloat4 a0 = f0[0];
        nfloat4 a1 = f0[dx * 8];
        nfloat4 a2 = f0[dyw * 8];
        nfloat4 a3 = f0[(dx + dyw) * 8];

        nfloat4 o;
        o.x = ((w4.x * a0.x + w4.y * a1.x) + w4.z * a2.x) + w4.w * a3.x;
        o.y = ((w4.x * a0.y + w4.y * a1.y) + w4.z * a2.y) + w4.w * a3.y;
        o.z = ((w4.x * a0.z + w4.y * a1.z) + w4.z * a2.z) + w4.w * a3.z;
        o.w = ((w4.x * a0.w + w4.y * a1.w) + w4.z * a2.w) + w4.w * a3.w;

        int cb = c4 * 4;
        s_out[(cb + 0) * 65 + bl_] = o.x;
        s_out[(cb + 1) * 65 + bl_] = o.y;
        s_out[(cb + 2) * 65 + bl_] = o.z;
        s_out[(cb + 3) * 65 + bl_] = o.w;
    }
    __syncthreads();

    // Store: 512 float4-units along bins. unit v: c=v>>4, b4=(v&15)*4.
    // Wave = 4 c-rows x 256B contiguous chunks -> dwordx4 stores.
    int obase = n * (C_ * NB_) + seg * 64;
#pragma unroll
    for (int i = 0; i < 2; ++i) {
        int v  = i * 256 + t;
        int cc = v >> 4;
        int b4 = (v & 15) * 4;
        nfloat4 o;
        o.x = s_out[cc * 65 + b4 + 0];
        o.y = s_out[cc * 65 + b4 + 1];
        o.z = s_out[cc * 65 + b4 + 2];
        o.w = s_out[cc * 65 + b4 + 3];
        __builtin_nontemporal_store(o, (nfloat4*)&out[obase + cc * NB_ + b4]);
    }
}

// Fallback (R1, known-good): thread per output, full geometry recompute.
__global__ __launch_bounds__(256) void roi_prep(const float* __restrict__ rois,
                                                float* __restrict__ g, int N) {
    int n = blockIdx.x * 256 + threadIdx.x;
    if (n < N) roi_transform(rois, n, g);
}

__global__ __launch_bounds__(256) void rroi_fallback(
    const float* __restrict__ feat, const float* __restrict__ g,
    float* __restrict__ out, int total) {
#pragma clang fp contract(off)
    int idx = blockIdx.x * 256 + threadIdx.x;
    if (idx >= total) return;
    int pw = idx & 63;
    int ph = (idx >> 6) & 7;
    int c  = (idx >> 9) & 31;
    int n  = idx >> 14;
    const float* gg = g + n * 8;
    int   b   = (int)gg[0];
    float M00 = gg[1], M01 = gg[2], M02 = gg[3];
    float M10 = gg[4], M11 = gg[5], M12 = gg[6];
    float pwf  = (float)pw, phf = (float)ph;
    float pwf1 = pwf + 1.0f, phf1 = phf + 1.0f;
    float X0 = (M00 * pwf  + M01 * phf ) + M02;
    float X1 = (M00 * pwf  + M01 * phf1) + M02;
    float X2 = (M00 * pwf1 + M01 * phf ) + M02;
    float X3 = (M00 * pwf1 + M01 * phf1) + M02;
    float Y0 = (M10 * pwf  + M11 * phf ) + M12;
    float Y1 = (M10 * pwf  + M11 * phf1) + M12;
    float Y2 = (M10 * pwf1 + M11 * phf ) + M12;
    float Y3 = (M10 * pwf1 + M11 * phf1) + M12;
    float minX = fminf(fminf(X0, X1), fminf(X2, X3));
    float maxX = fmaxf(fmaxf(X0, X1), fmaxf(X2, X3));
    float minY = fminf(fminf(Y0, Y1), fminf(Y2, Y3));
    float maxY = fmaxf(fmaxf(Y0, Y1), fmaxf(Y2, Y3));
    float left   = fmaxf(floorf(minX + 0.5f), 0.0f);
    float right  = fminf(floorf(maxX + 0.5f), (float)(W_ - 1));
    float top    = fmaxf(floorf(minY + 0.5f), 0.0f);
    float bottom = fminf(floorf(maxY + 0.5f), (float)(H_ - 1));
    float bcx = (left + right) * 0.5f;
    float bcy = (top + bottom) * 0.5f;
    float bl = floorf(bcx), br = ceilf(bcx);
    float bt = floorf(bcy), bb = ceilf(bcy);
    float rx = bcx - bl;
    float ry = bcy - bt;
    const float* fc = feat + (size_t)(b * C_ + c) * HW_;
    auto gat = [&](float yi, float xi) -> float {
        bool valid = (yi > -1.0f) && (xi > -1.0f) && (yi < (float)H_) &&
                     (xi < (float)W_);
        int yc = (int)fminf(fmaxf(yi, 0.0f), (float)(H_ - 1));
        int xc = (int)fminf(fmaxf(xi, 0.0f), (float)(W_ - 1));
        float v = fc[yc * W_ + xc];
        return valid ? v : 0.0f;
    };
    float vlt = gat(bt, bl);
    float vrt = gat(bt, br);
    float vlb = gat(bb, bl);
    float vrb = gat(bb, br);
    float omrx = 1.0f - rx, omry = 1.0f - ry;
    float o = (((omrx * omry) * vlt + (rx * omry) * vrt) + (omrx * ry) * vlb) +
              (rx * ry) * vrb;
    out[idx] = o;
}

extern "C" void kernel_launch(void* const* d_in, const int* in_sizes, int n_in,
                              void* d_out, int out_size, void* d_ws,
                              size_t ws_size, hipStream_t stream) {
    const float* feat = (const float*)d_in[0];
    const float* rois = (const float*)d_in[1];
    float* out = (float*)d_out;
    int N = in_sizes[1] / 6;
    int B = in_sizes[0] / (C_ * HW_);

    size_t gBytes  = ((size_t)N * 8 * sizeof(float) + 255) & ~(size_t)255;
    size_t ftBytes = (size_t)B * HW_ * C_ * sizeof(float);
    size_t needed  = gBytes + ftBytes;

    if (ws_size >= needed) {
        float* g  = (float*)d_ws;
        float* ft = (float*)((char*)d_ws + gBytes);
        hipLaunchKernelGGL(transpose_nhwc, dim3(HW_ / 64, B), dim3(256), 0,
                           stream, feat, ft, rois, g, N);
        hipLaunchKernelGGL(rroi_nhwc, dim3(N * 8), dim3(256), 0, stream, ft, g,
                           out);
    } else {
        float* g = (float*)d_ws;  // N*8 floats
        hipLaunchKernelGGL(roi_prep, dim3((N + 255) / 256), dim3(256), 0,
                           stream, rois, g, N);
        hipLaunchKernelGGL(rroi_fallback, dim3((out_size + 255) / 256),
                           dim3(256), 0, stream, feat, g, out, out_size);
    }
}

// Round 7
// 101.259 us; speedup vs baseline: 1.8147x; 1.0446x over previous
//
#include <hip/hip_runtime.h>
#include <math.h>

// RRoIAlign: features (8,32,160,160) f32, rois (1024,6) f32
// out (1024,32,8,64) f32.  POOLED_H=8, POOLED_W=64, SPATIAL_SCALE=0.25
//
// R7: fp16 NHWC intermediate (halves the transpose-trick's HBM overhead:
// ft write 26->13 MB, ft read 26->13 MB). Feature fp16 rounding error
// <= |v|*2^-11 ~ 0.003 << 0.101 threshold; geometry stays bit-exact.
//   transpose_nhwc : NCHW f32 -> NHWC fp16 (B,HW,32); first blocks also
//                    compute per-roi affine transforms g[].
//   rroi_nhwc      : block = 64 bins of one roi; t<64 computes geometry into
//                    LDS; gather = 8 bins x 8 lanes, 4 halfs (dwordx2)/lane;
//                    f32 blend (frozen order); LDS [c][bin] -> dwordx4 NT
//                    stores.
//
// NUMERICS (frozen since R1): geometry fp contract(off) + reference op order;
// trig double->f32; blend ((w0*a+w1*b)+w2*c)+w3*d contract off. Do not
// re-order. absmax was 0.0 with f32 intermediate; fp16 adds ~3e-3.

#define C_ 32
#define H_ 160
#define W_ 160
#define PH_ 8
#define PW_ 64
#define HW_ (H_ * W_)
#define NB_ (PH_ * PW_)  // 512 bins per roi

typedef float nfloat4 __attribute__((ext_vector_type(4)));
typedef _Float16 half4 __attribute__((ext_vector_type(4)));   // 8 B
typedef _Float16 half8 __attribute__((ext_vector_type(8)));   // 16 B

__device__ __forceinline__ void roi_transform(const float* __restrict__ rois,
                                              int n, float* __restrict__ g) {
#pragma clang fp contract(off)
    const float* r = rois + n * 6;
    float bidx = r[0];
    float cx = r[1], cy = r[2], hh = r[3], ww = r[4], ang = r[5];
    float theta = ang * 0.017453292519943295f;
    double td = (double)theta;
    float a = (float)cos(td);
    float s = (float)sin(td);
    float Sx = (ww * 0.25f) / 64.0f;
    float Sy = (hh * 0.25f) / 8.0f;
    float Dx = cx * 0.25f;
    float Dy = cy * 0.25f;
    float M00 = a * Sx;
    float M01 = s * Sy;
    float M02 = ((M00 * -32.0f) + (M01 * -4.0f)) + Dx;
    float M10 = (-s) * Sx;
    float M11 = a * Sy;
    float M12 = ((M10 * -32.0f) + (M11 * -4.0f)) + Dy;
    float* o = g + n * 8;
    o[0] = bidx;
    o[1] = M00; o[2] = M01; o[3] = M02;
    o[4] = M10; o[5] = M11; o[6] = M12;
    o[7] = 0.0f;
}

// NCHW f32 (B,32,25600) -> NHWC fp16 (B,25600,32).
// Blocks (x<ceil(N/256), y==0) also compute roi transforms into g.
__global__ __launch_bounds__(256) void transpose_nhwc(
    const float* __restrict__ feat, _Float16* __restrict__ ft,
    const float* __restrict__ rois, float* __restrict__ g, int N) {
    __shared__ float tile[C_][65];
    int t = threadIdx.x;

    if (blockIdx.y == 0) {
        int n = blockIdx.x * 256 + t;
        if (n < N) roi_transform(rois, n, g);
    }

    int b   = blockIdx.y;
    int hw0 = blockIdx.x * 64;

    // read: 512 float4-units along hw. unit v: c=v>>4, w4=(v&15)*4
#pragma unroll
    for (int i = 0; i < 2; ++i) {
        int v  = i * 256 + t;
        int c  = v >> 4;
        int w4 = (v & 15) * 4;
        const nfloat4 f = __builtin_nontemporal_load(
            (const nfloat4*)&feat[((b * C_ + c) * HW_) + hw0 + w4]);
        tile[c][w4 + 0] = f.x;
        tile[c][w4 + 1] = f.y;
        tile[c][w4 + 2] = f.z;
        tile[c][w4 + 3] = f.w;
    }
    __syncthreads();

    // write: thread t -> pixel p=t>>2, channels c8=(t&3)*8; one 16B store.
    {
        int p  = t >> 2;
        int c8 = (t & 3) * 8;
        half8 o;
#pragma unroll
        for (int k = 0; k < 8; ++k) o[k] = (_Float16)tile[c8 + k][p];
        *(half8*)&ft[((size_t)b * HW_ + hw0 + p) * C_ + c8] = o;
    }
}

// Block = 64 consecutive bins of one roi. 256 threads.
__global__ __launch_bounds__(256) void rroi_nhwc(
    const _Float16* __restrict__ ft, const float* __restrict__ g,
    float* __restrict__ out) {
    __shared__ int    s_pos[64];
    __shared__ int    s_dxy[64];
    __shared__ float4 s_w[64];
    __shared__ float  s_out[C_ * 65];  // [c][bin], pad 65 (<=2-way, free)

    int blk = blockIdx.x;
    int n   = blk >> 3;
    int seg = blk & 7;
    int t   = threadIdx.x;

    if (t < 64) {
#pragma clang fp contract(off)
        int bin = seg * 64 + t;  // = ph*64+pw
        int pw = bin & 63;
        int ph = bin >> 6;
        const float* gg = g + n * 8;
        int   b   = (int)gg[0];
        float M00 = gg[1], M01 = gg[2], M02 = gg[3];
        float M10 = gg[4], M11 = gg[5], M12 = gg[6];

        float pwf  = (float)pw, phf = (float)ph;
        float pwf1 = pwf + 1.0f, phf1 = phf + 1.0f;
        // corners, reference op order: (M00*px + M01*py) + M02
        float X0 = (M00 * pwf  + M01 * phf ) + M02;
        float X1 = (M00 * pwf  + M01 * phf1) + M02;
        float X2 = (M00 * pwf1 + M01 * phf ) + M02;
        float X3 = (M00 * pwf1 + M01 * phf1) + M02;
        float Y0 = (M10 * pwf  + M11 * phf ) + M12;
        float Y1 = (M10 * pwf  + M11 * phf1) + M12;
        float Y2 = (M10 * pwf1 + M11 * phf ) + M12;
        float Y3 = (M10 * pwf1 + M11 * phf1) + M12;

        float minX = fminf(fminf(X0, X1), fminf(X2, X3));
        float maxX = fmaxf(fmaxf(X0, X1), fmaxf(X2, X3));
        float minY = fminf(fminf(Y0, Y1), fminf(Y2, Y3));
        float maxY = fmaxf(fmaxf(Y0, Y1), fmaxf(Y2, Y3));

        float left   = fmaxf(floorf(minX + 0.5f), 0.0f);
        float right  = fminf(floorf(maxX + 0.5f), (float)(W_ - 1));
        float top    = fmaxf(floorf(minY + 0.5f), 0.0f);
        float bottom = fminf(floorf(maxY + 0.5f), (float)(H_ - 1));

        float bcx = (left + right) * 0.5f;
        float bcy = (top + bottom) * 0.5f;
        float bl = floorf(bcx), br = ceilf(bcx);
        float bt = floorf(bcy), bb = ceilf(bcy);
        float rx = bcx - bl;  // exactly 0 or 0.5
        float ry = bcy - bt;

        bool v_l = (bl > -1.0f) && (bl < (float)W_);
        bool v_r = (br > -1.0f) && (br < (float)W_);
        bool v_t = (bt > -1.0f) && (bt < (float)H_);
        bool v_b = (bb > -1.0f) && (bb < (float)H_);

        float omrx = 1.0f - rx, omry = 1.0f - ry;
        float4 w4;
        w4.x = (v_t && v_l) ? (omrx * omry) : 0.0f;
        w4.y = (v_t && v_r) ? (rx   * omry) : 0.0f;
        w4.z = (v_b && v_l) ? (omrx * ry  ) : 0.0f;
        w4.w = (v_b && v_r) ? (rx   * ry  ) : 0.0f;

        int xl = (int)fminf(fmaxf(bl, 0.0f), (float)(W_ - 1));
        int xr = (int)fminf(fmaxf(br, 0.0f), (float)(W_ - 1));
        int yt = (int)fminf(fmaxf(bt, 0.0f), (float)(H_ - 1));
        int yb = (int)fminf(fmaxf(bb, 0.0f), (float)(H_ - 1));

        s_pos[t] = b * HW_ + yt * W_ + xl;  // NHWC pixel index
        s_dxy[t] = (xr - xl) | (((yb - yt) * W_) << 16);
        s_w[t]   = w4;
    }
    __syncthreads();

    // Gather+blend: 512 units. unit u: bin=u>>3, c4=u&7 (4 channels each).
    // Per corner per wave: 8 bins x 64B contiguous -> coalesced dwordx2.
#pragma unroll
    for (int i = 0; i < 2; ++i) {
#pragma clang fp contract(off)
        int u   = i * 256 + t;
        int bl_ = u >> 3;
        int c4  = u & 7;
        int pos = s_pos[bl_];
        int d   = s_dxy[bl_];
        int dx  = d & 0xffff;
        int dyw = (int)((unsigned)d >> 16);
        float4 w4 = s_w[bl_];

        const half4* f0 = (const half4*)(ft + (size_t)pos * C_) + c4;
        half4 a0 = f0[0];
        half4 a1 = f0[dx * 8];
        half4 a2 = f0[dyw * 8];
        half4 a3 = f0[(dx + dyw) * 8];

        int cb = c4 * 4;
#pragma unroll
        for (int k = 0; k < 4; ++k) {
            float o = ((w4.x * (float)a0[k] + w4.y * (float)a1[k]) +
                       w4.z * (float)a2[k]) +
                      w4.w * (float)a3[k];
            s_out[(cb + k) * 65 + bl_] = o;
        }
    }
    __syncthreads();

    // Store: 512 float4-units along bins. unit v: c=v>>4, b4=(v&15)*4.
    int obase = n * (C_ * NB_) + seg * 64;
#pragma unroll
    for (int i = 0; i < 2; ++i) {
        int v  = i * 256 + t;
        int cc = v >> 4;
        int b4 = (v & 15) * 4;
        nfloat4 o;
        o.x = s_out[cc * 65 + b4 + 0];
        o.y = s_out[cc * 65 + b4 + 1];
        o.z = s_out[cc * 65 + b4 + 2];
        o.w = s_out[cc * 65 + b4 + 3];
        __builtin_nontemporal_store(o, (nfloat4*)&out[obase + cc * NB_ + b4]);
    }
}

// Fallback (R1, known-good): thread per output, full geometry recompute.
__global__ __launch_bounds__(256) void roi_prep(const float* __restrict__ rois,
                                                float* __restrict__ g, int N) {
    int n = blockIdx.x * 256 + threadIdx.x;
    if (n < N) roi_transform(rois, n, g);
}

__global__ __launch_bounds__(256) void rroi_fallback(
    const float* __restrict__ feat, const float* __restrict__ g,
    float* __restrict__ out, int total) {
#pragma clang fp contract(off)
    int idx = blockIdx.x * 256 + threadIdx.x;
    if (idx >= total) return;
    int pw = idx & 63;
    int ph = (idx >> 6) & 7;
    int c  = (idx >> 9) & 31;
    int n  = idx >> 14;
    const float* gg = g + n * 8;
    int   b   = (int)gg[0];
    float M00 = gg[1], M01 = gg[2], M02 = gg[3];
    float M10 = gg[4], M11 = gg[5], M12 = gg[6];
    float pwf  = (float)pw, phf = (float)ph;
    float pwf1 = pwf + 1.0f, phf1 = phf + 1.0f;
    float X0 = (M00 * pwf  + M01 * phf ) + M02;
    float X1 = (M00 * pwf  + M01 * phf1) + M02;
    float X2 = (M00 * pwf1 + M01 * phf ) + M02;
    float X3 = (M00 * pwf1 + M01 * phf1) + M02;
    float Y0 = (M10 * pwf  + M11 * phf ) + M12;
    float Y1 = (M10 * pwf  + M11 * phf1) + M12;
    float Y2 = (M10 * pwf1 + M11 * phf ) + M12;
    float Y3 = (M10 * pwf1 + M11 * phf1) + M12;
    float minX = fminf(fminf(X0, X1), fminf(X2, X3));
    float maxX = fmaxf(fmaxf(X0, X1), fmaxf(X2, X3));
    float minY = fminf(fminf(Y0, Y1), fminf(Y2, Y3));
    float maxY = fmaxf(fmaxf(Y0, Y1), fmaxf(Y2, Y3));
    float left   = fmaxf(floorf(minX + 0.5f), 0.0f);
    float right  = fminf(floorf(maxX + 0.5f), (float)(W_ - 1));
    float top    = fmaxf(floorf(minY + 0.5f), 0.0f);
    float bottom = fminf(floorf(maxY + 0.5f), (float)(H_ - 1));
    float bcx = (left + right) * 0.5f;
    float bcy = (top + bottom) * 0.5f;
    float bl = floorf(bcx), br = ceilf(bcx);
    float bt = floorf(bcy), bb = ceilf(bcy);
    float rx = bcx - bl;
    float ry = bcy - bt;
    const float* fc = feat + (size_t)(b * C_ + c) * HW_;
    auto gat = [&](float yi, float xi) -> float {
        bool valid = (yi > -1.0f) && (xi > -1.0f) && (yi < (float)H_) &&
                     (xi < (float)W_);
        int yc = (int)fminf(fmaxf(yi, 0.0f), (float)(H_ - 1));
        int xc = (int)fminf(fmaxf(xi, 0.0f), (float)(W_ - 1));
        float v = fc[yc * W_ + xc];
        return valid ? v : 0.0f;
    };
    float vlt = gat(bt, bl);
    float vrt = gat(bt, br);
    float vlb = gat(bb, bl);
    float vrb = gat(bb, br);
    float omrx = 1.0f - rx, omry = 1.0f - ry;
    float o = (((omrx * omry) * vlt + (rx * omry) * vrt) + (omrx * ry) * vlb) +
              (rx * ry) * vrb;
    out[idx] = o;
}

extern "C" void kernel_launch(void* const* d_in, const int* in_sizes, int n_in,
                              void* d_out, int out_size, void* d_ws,
                              size_t ws_size, hipStream_t stream) {
    const float* feat = (const float*)d_in[0];
    const float* rois = (const float*)d_in[1];
    float* out = (float*)d_out;
    int N = in_sizes[1] / 6;
    int B = in_sizes[0] / (C_ * HW_);

    size_t gBytes  = ((size_t)N * 8 * sizeof(float) + 255) & ~(size_t)255;
    size_t ftBytes = (size_t)B * HW_ * C_ * sizeof(_Float16);
    size_t needed  = gBytes + ftBytes;

    if (ws_size >= needed) {
        float*    g  = (float*)d_ws;
        _Float16* ft = (_Float16*)((char*)d_ws + gBytes);
        hipLaunchKernelGGL(transpose_nhwc, dim3(HW_ / 64, B), dim3(256), 0,
                           stream, feat, ft, rois, g, N);
        hipLaunchKernelGGL(rroi_nhwc, dim3(N * 8), dim3(256), 0, stream, ft, g,
                           out);
    } else {
        float* g = (float*)d_ws;  // N*8 floats
        hipLaunchKernelGGL(roi_prep, dim3((N + 255) / 256), dim3(256), 0,
                           stream, rois, g, N);
        hipLaunchKernelGGL(rroi_fallback, dim3((out_size + 255) / 256),
                           dim3(256), 0, stream, feat, g, out, out_size);
    }
}